// Round 1
// baseline (1124.943 us; speedup 1.0000x reference)
//
#include <hip/hip_runtime.h>
#include <hip/hip_bf16.h>

// ---------------------------------------------------------------------------
// GAT forward: 3 layers, N=100k nodes, D=64, E=1.6M edges (+N self loops).
// Strategy: build dst-CSR once (edges fixed across layers), then per layer:
//   gemm_k:  h = x @ W, fused e_s = h.a_s, e_d = h.a_d  (wave per node)
//   agg_k :  segment softmax over incoming edges + weighted gather of h[src]
//            (wave per dst node, lane = dim, recompute e instead of storing)
// dtype of float inputs/outputs (f32 vs bf16) detected on-device; everything
// internal is f32 in workspace.
// ---------------------------------------------------------------------------

__global__ __launch_bounds__(256) void detect_bf16_k(const unsigned int* raw, int* flag) {
    __shared__ int sc;
    if (threadIdx.x == 0) sc = 0;
    __syncthreads();
    int c = 0;
    for (int i = threadIdx.x; i < 4096; i += 256) {
        unsigned int b = (raw[i] >> 8) & 0x7Fu;   // bits 15:8, sign masked
        if (b >= 0x3Bu && b <= 0x3Fu) c++;        // bf16 exponent byte range
    }
    atomicAdd(&sc, c);
    __syncthreads();
    if (threadIdx.x == 0) *flag = (sc > 2048) ? 1 : 0;
}

__device__ inline float load_in(const void* p, int i, int isbf) {
    if (isbf) {
        unsigned short u = ((const unsigned short*)p)[i];
        return __uint_as_float(((unsigned int)u) << 16);
    }
    return ((const float*)p)[i];
}

__global__ __launch_bounds__(256) void conv_emb_k(const void* emb, float* x, float* outacc,
                                                  int n, const int* flag) {
    int i = blockIdx.x * 256 + threadIdx.x;
    if (i >= n) return;
    float v = load_in(emb, i, *flag);
    x[i] = v;
    outacc[i] = v;   // mean starts with x0 = emb
}

__global__ __launch_bounds__(256) void conv_params_k(const void* W, const void* as_, const void* ad_,
                                                     const void* b_, float* Wf, float* asf, float* adf,
                                                     float* bf, int nw, int na, const int* flag) {
    int i = blockIdx.x * 256 + threadIdx.x;
    int isbf = *flag;
    if (i < nw) Wf[i] = load_in(W, i, isbf);
    if (i < na) {
        asf[i] = load_in(as_, i, isbf);
        adf[i] = load_in(ad_, i, isbf);
        bf[i]  = load_in(b_,  i, isbf);
    }
}

// ---- CSR build -------------------------------------------------------------

__global__ __launch_bounds__(256) void init_cnt_k(int* cnt, int n) {
    int i = blockIdx.x * 256 + threadIdx.x;
    if (i < n) cnt[i] = 1;   // self-loop pre-counted
}

__global__ __launch_bounds__(256) void count_k(const int* dst, int* cnt, int E) {
    int i = blockIdx.x * 256 + threadIdx.x;
    if (i < E) atomicAdd(&cnt[dst[i]], 1);
}

__global__ __launch_bounds__(256) void scan_block_k(const int* cnt, int* rowptr, int* bsums, int n) {
    __shared__ int s[256];
    int gid = blockIdx.x * 256 + threadIdx.x;
    int v = (gid < n) ? cnt[gid] : 0;
    s[threadIdx.x] = v;
    __syncthreads();
    for (int off = 1; off < 256; off <<= 1) {
        int t = (threadIdx.x >= off) ? s[threadIdx.x - off] : 0;
        __syncthreads();
        s[threadIdx.x] += t;
        __syncthreads();
    }
    if (gid < n) rowptr[gid] = s[threadIdx.x] - v;            // exclusive
    if (threadIdx.x == 255) bsums[blockIdx.x] = s[255];
}

__global__ __launch_bounds__(512) void scan_sums_k(int* bs, int nb) {
    __shared__ int s[512];
    int v = (threadIdx.x < nb) ? bs[threadIdx.x] : 0;
    s[threadIdx.x] = v;
    __syncthreads();
    for (int off = 1; off < 512; off <<= 1) {
        int t = (threadIdx.x >= off) ? s[threadIdx.x - off] : 0;
        __syncthreads();
        s[threadIdx.x] += t;
        __syncthreads();
    }
    if (threadIdx.x < nb) bs[threadIdx.x] = s[threadIdx.x] - v;  // exclusive
}

__global__ __launch_bounds__(256) void scan_add_k(int* rowptr, const int* bs, int* cursor,
                                                  int n, int total) {
    int i = blockIdx.x * 256 + threadIdx.x;
    if (i < n) {
        int r = rowptr[i] + bs[blockIdx.x];
        rowptr[i] = r;
        cursor[i] = r;
    }
    if (i == 0) rowptr[n] = total;
}

__global__ __launch_bounds__(256) void scatter_k(const int* src, const int* dst, int* cursor,
                                                 int* col, int E, int N) {
    int i = blockIdx.x * 256 + threadIdx.x;
    if (i < E) {
        int pos = atomicAdd(&cursor[dst[i]], 1);
        col[pos] = src[i];
    } else if (i < E + N) {
        int d = i - E;
        int pos = atomicAdd(&cursor[d], 1);
        col[pos] = d;                         // self loop
    }
}

// ---- per-layer compute -----------------------------------------------------

// h = x @ W  (D=64), fused per-node scores es = h.a_s, ed = h.a_d.
// One wave per node-row; W staged in LDS; x row broadcast via shuffles.
__global__ __launch_bounds__(256) void gemm_k(const float* __restrict__ x, const float* __restrict__ W,
                                              const float* __restrict__ asv, const float* __restrict__ adv,
                                              float* __restrict__ h, float* __restrict__ es,
                                              float* __restrict__ ed, int n) {
    __shared__ float Wl[4096];
    __shared__ float asl[64], adl[64];
    for (int i = threadIdx.x; i < 4096; i += 256) Wl[i] = W[i];
    if (threadIdx.x < 64) { asl[threadIdx.x] = asv[threadIdx.x]; adl[threadIdx.x] = adv[threadIdx.x]; }
    __syncthreads();
    int lane = threadIdx.x & 63;
    int wv = threadIdx.x >> 6;
    float a_s = asl[lane], a_d = adl[lane];
    for (int node = blockIdx.x * 4 + wv; node < n; node += gridDim.x * 4) {
        float xv = x[(size_t)node * 64 + lane];
        float acc = 0.f;
        #pragma unroll
        for (int k = 0; k < 64; ++k)
            acc = fmaf(__shfl(xv, k), Wl[k * 64 + lane], acc);
        h[(size_t)node * 64 + lane] = acc;
        float s1 = acc * a_s, s2 = acc * a_d;
        #pragma unroll
        for (int off = 32; off; off >>= 1) {
            s1 += __shfl_xor(s1, off);
            s2 += __shfl_xor(s2, off);
        }
        if (lane == 0) { es[node] = s1; ed[node] = s2; }
    }
}

// One wave per dst node. Phase A: max(e); B: sum exp(e-m); C: weighted gather.
__global__ __launch_bounds__(256) void agg_k(const float* __restrict__ h, const float* __restrict__ es,
                                             const float* __restrict__ ed, const int* __restrict__ rowptr,
                                             const int* __restrict__ col, const float* __restrict__ bias,
                                             float* __restrict__ x, float* __restrict__ outacc, int n) {
    int gw = (blockIdx.x * 256 + threadIdx.x) >> 6;
    int lane = threadIdx.x & 63;
    if (gw >= n) return;
    int start = rowptr[gw], end = rowptr[gw + 1];
    float edd = ed[gw];

    float m = -1e30f;
    for (int k = start + lane; k < end; k += 64) {
        float e = es[col[k]] + edd;
        e = e > 0.f ? e : 0.2f * e;
        m = fmaxf(m, e);
    }
    #pragma unroll
    for (int off = 32; off; off >>= 1) m = fmaxf(m, __shfl_xor(m, off));

    float sum = 0.f;
    for (int k = start + lane; k < end; k += 64) {
        float e = es[col[k]] + edd;
        e = e > 0.f ? e : 0.2f * e;
        sum += __expf(e - m);
    }
    #pragma unroll
    for (int off = 32; off; off >>= 1) sum += __shfl_xor(sum, off);
    float inv = 1.f / (sum + 1e-16f);

    float acc = 0.f;
    for (int k = start; k < end; ++k) {
        int s = col[k];                      // uniform across wave -> broadcast
        float e = es[s] + edd;
        e = e > 0.f ? e : 0.2f * e;
        float a = __expf(e - m) * inv;
        acc = fmaf(a, h[(size_t)s * 64 + lane], acc);  // 256B coalesced
    }
    acc += bias[lane];
    float y = acc > 0.f ? acc : (__expf(acc) - 1.f);   // elu
    x[(size_t)gw * 64 + lane] = y;
    outacc[(size_t)gw * 64 + lane] += y;
}

__global__ __launch_bounds__(256) void finalize_k(const float* outacc, void* out, int n, const int* flag) {
    int i = blockIdx.x * 256 + threadIdx.x;
    if (i >= n) return;
    float v = outacc[i] * 0.25f;             // mean over [x0,x1,x2,x3]
    if (*flag) ((__hip_bfloat16*)out)[i] = __float2bfloat16(v);
    else       ((float*)out)[i] = v;
}

// ---------------------------------------------------------------------------

extern "C" void kernel_launch(void* const* d_in, const int* in_sizes, int n_in,
                              void* d_out, int out_size, void* d_ws, size_t ws_size,
                              hipStream_t stream) {
    const int*  edge = (const int*)d_in[0];
    const void* emb  = d_in[1];
    const void* W    = d_in[2];
    const void* as_  = d_in[3];
    const void* ad_  = d_in[4];
    const void* b_   = d_in[5];

    const int E = in_sizes[0] / 2;
    const int N = in_sizes[1] / 64;
    const int L = in_sizes[2] / 4096;
    const size_t N64 = (size_t)N * 64;

    char* p = (char*)d_ws;
    auto take = [&](size_t bytes) { char* r = p; p += (bytes + 255) & ~(size_t)255; return r; };
    float* x      = (float*)take(N64 * 4);
    float* h      = (float*)take(N64 * 4);
    float* outacc = (float*)take(N64 * 4);
    float* es     = (float*)take((size_t)N * 4);
    float* ed     = (float*)take((size_t)N * 4);
    float* Wf     = (float*)take((size_t)L * 4096 * 4);
    float* asf    = (float*)take((size_t)L * 64 * 4);
    float* adf    = (float*)take((size_t)L * 64 * 4);
    float* bf     = (float*)take((size_t)L * 64 * 4);
    int* cursor   = (int*)take((size_t)N * 4);
    int* rowptr   = (int*)take((size_t)(N + 1) * 4);
    int* col      = (int*)take((size_t)(E + N) * 4);
    int* bsums    = (int*)take(512 * 4);
    int* flag     = (int*)take(4);

    const int* srcp = edge;
    const int* dstp = edge + E;

    detect_bf16_k<<<1, 256, 0, stream>>>((const unsigned int*)emb, flag);
    conv_emb_k<<<(int)((N64 + 255) / 256), 256, 0, stream>>>(emb, x, outacc, (int)N64, flag);
    conv_params_k<<<(L * 4096 + 255) / 256, 256, 0, stream>>>(W, as_, ad_, b_, Wf, asf, adf, bf,
                                                              L * 4096, L * 64, flag);

    // CSR build (dst-grouped), reused by all layers
    init_cnt_k<<<(N + 255) / 256, 256, 0, stream>>>(cursor, N);
    count_k<<<(E + 255) / 256, 256, 0, stream>>>(dstp, cursor, E);
    int nb1 = (N + 255) / 256;                 // 391 <= 512
    scan_block_k<<<nb1, 256, 0, stream>>>(cursor, rowptr, bsums, N);
    scan_sums_k<<<1, 512, 0, stream>>>(bsums, nb1);
    scan_add_k<<<nb1, 256, 0, stream>>>(rowptr, bsums, cursor, N, E + N);
    scatter_k<<<(E + N + 255) / 256, 256, 0, stream>>>(srcp, dstp, cursor, col, E, N);

    for (int l = 0; l < L; ++l) {
        gemm_k<<<1024, 256, 0, stream>>>(x, Wf + (size_t)l * 4096, asf + l * 64, adf + l * 64,
                                         h, es, ed, N);
        agg_k<<<(N + 3) / 4, 256, 0, stream>>>(h, es, ed, rowptr, col, bf + l * 64, x, outacc, N);
    }

    finalize_k<<<(int)((N64 + 255) / 256), 256, 0, stream>>>(outacc, d_out, (int)N64, flag);
}

// Round 2
// 793.969 us; speedup vs baseline: 1.4169x; 1.4169x over previous
//
#include <hip/hip_runtime.h>
#include <hip/hip_bf16.h>

// ---------------------------------------------------------------------------
// GAT forward: 3 layers, N=100k nodes, D=64, E=1.6M edges (+N self loops).
// dst-CSR built once per launch; per layer: gemm (h=xW + fused scores), then
// agg (segment softmax + weighted gather). agg fast path caches the whole
// edge list of a node in registers (deg<=64 covers ~all nodes) and gathers
// h rows 4-edges-at-a-time with float4 loads (16 lanes x 16B per edge).
// ---------------------------------------------------------------------------

__global__ __launch_bounds__(256) void detect_bf16_k(const unsigned int* raw, int* flag) {
    __shared__ int sc;
    if (threadIdx.x == 0) sc = 0;
    __syncthreads();
    int c = 0;
    for (int i = threadIdx.x; i < 4096; i += 256) {
        unsigned int b = (raw[i] >> 8) & 0x7Fu;   // bits 15:8, sign masked
        if (b >= 0x3Bu && b <= 0x3Fu) c++;        // bf16 exponent byte range
    }
    atomicAdd(&sc, c);
    __syncthreads();
    if (threadIdx.x == 0) *flag = (sc > 2048) ? 1 : 0;
}

__device__ inline float load_in(const void* p, int i, int isbf) {
    if (isbf) {
        unsigned short u = ((const unsigned short*)p)[i];
        return __uint_as_float(((unsigned int)u) << 16);
    }
    return ((const float*)p)[i];
}

__device__ inline unsigned short f2bf(float v) {
    __hip_bfloat16 b = __float2bfloat16(v);
    return *reinterpret_cast<unsigned short*>(&b);
}

// also initializes the CSR counter array (self-loop pre-counted)
__global__ __launch_bounds__(256) void conv_emb_k(const void* emb, float* x, float* outacc,
                                                  int* cnt, int n, int N, const int* flag) {
    int i = blockIdx.x * 256 + threadIdx.x;
    if (i >= n) return;
    float v = load_in(emb, i, *flag);
    x[i] = v;
    outacc[i] = v;   // mean starts with x0 = emb
    if (i < N) cnt[i] = 1;
}

__global__ __launch_bounds__(256) void conv_params_k(const void* W, const void* as_, const void* ad_,
                                                     const void* b_, float* Wf, float* asf, float* adf,
                                                     float* bf, int nw, int na, const int* flag) {
    int i = blockIdx.x * 256 + threadIdx.x;
    int isbf = *flag;
    if (i < nw) Wf[i] = load_in(W, i, isbf);
    if (i < na) {
        asf[i] = load_in(as_, i, isbf);
        adf[i] = load_in(ad_, i, isbf);
        bf[i]  = load_in(b_,  i, isbf);
    }
}

// ---- CSR build -------------------------------------------------------------

__global__ __launch_bounds__(256) void count_k(const int* dst, int* cnt, int E) {
    int i = blockIdx.x * 256 + threadIdx.x;
    if (i < E) atomicAdd(&cnt[dst[i]], 1);
}

__global__ __launch_bounds__(256) void scan_block_k(const int* cnt, int* rowptr, int* bsums, int n) {
    __shared__ int s[256];
    int gid = blockIdx.x * 256 + threadIdx.x;
    int v = (gid < n) ? cnt[gid] : 0;
    s[threadIdx.x] = v;
    __syncthreads();
    for (int off = 1; off < 256; off <<= 1) {
        int t = (threadIdx.x >= off) ? s[threadIdx.x - off] : 0;
        __syncthreads();
        s[threadIdx.x] += t;
        __syncthreads();
    }
    if (gid < n) rowptr[gid] = s[threadIdx.x] - v;            // exclusive
    if (threadIdx.x == 255) bsums[blockIdx.x] = s[255];
}

__global__ __launch_bounds__(512) void scan_sums_k(int* bs, int nb) {
    __shared__ int s[512];
    int v = (threadIdx.x < nb) ? bs[threadIdx.x] : 0;
    s[threadIdx.x] = v;
    __syncthreads();
    for (int off = 1; off < 512; off <<= 1) {
        int t = (threadIdx.x >= off) ? s[threadIdx.x - off] : 0;
        __syncthreads();
        s[threadIdx.x] += t;
        __syncthreads();
    }
    if (threadIdx.x < nb) bs[threadIdx.x] = s[threadIdx.x] - v;  // exclusive
}

__global__ __launch_bounds__(256) void scan_add_k(int* rowptr, const int* bs, int* cursor,
                                                  int n, int total) {
    int i = blockIdx.x * 256 + threadIdx.x;
    if (i < n) {
        int r = rowptr[i] + bs[blockIdx.x];
        rowptr[i] = r;
        cursor[i] = r;
    }
    if (i == 0) rowptr[n] = total;
}

__global__ __launch_bounds__(256) void scatter_k(const int* src, const int* dst, int* cursor,
                                                 int* col, int E, int N) {
    int i = blockIdx.x * 256 + threadIdx.x;
    if (i < E) {
        int pos = atomicAdd(&cursor[dst[i]], 1);
        col[pos] = src[i];
    } else if (i < E + N) {
        int d = i - E;
        int pos = atomicAdd(&cursor[d], 1);
        col[pos] = d;                         // self loop
    }
}

// ---- per-layer compute -----------------------------------------------------

// h = x @ W  (D=64), fused per-node scores es = h.a_s, ed = h.a_d.
__global__ __launch_bounds__(256) void gemm_k(const float* __restrict__ x, const float* __restrict__ W,
                                              const float* __restrict__ asv, const float* __restrict__ adv,
                                              float* __restrict__ h, float* __restrict__ es,
                                              float* __restrict__ ed, int n) {
    __shared__ float Wl[4096];
    __shared__ float asl[64], adl[64];
    for (int i = threadIdx.x; i < 4096; i += 256) Wl[i] = W[i];
    if (threadIdx.x < 64) { asl[threadIdx.x] = asv[threadIdx.x]; adl[threadIdx.x] = adv[threadIdx.x]; }
    __syncthreads();
    int lane = threadIdx.x & 63;
    int wv = threadIdx.x >> 6;
    float a_s = asl[lane], a_d = adl[lane];
    for (int node = blockIdx.x * 4 + wv; node < n; node += gridDim.x * 4) {
        float xv = x[(size_t)node * 64 + lane];
        float acc = 0.f;
        #pragma unroll
        for (int k = 0; k < 64; ++k)
            acc = fmaf(__shfl(xv, k), Wl[k * 64 + lane], acc);
        h[(size_t)node * 64 + lane] = acc;
        float s1 = acc * a_s, s2 = acc * a_d;
        #pragma unroll
        for (int off = 32; off; off >>= 1) {
            s1 += __shfl_xor(s1, off);
            s2 += __shfl_xor(s2, off);
        }
        if (lane == 0) { es[node] = s1; ed[node] = s2; }
    }
}

__device__ inline float elu_f(float v) { return v > 0.f ? v : (__expf(v) - 1.f); }

// One wave per dst node. Fast path (deg<=64): edge list cached in registers,
// one gather pass for scores, then h gathered 4 edges/iter with float4 loads.
// write_out!=0 (last layer): skip x/outacc stores, emit final mean to out.
__global__ __launch_bounds__(256) void agg_k(const float* __restrict__ h, const float* __restrict__ es,
                                             const float* __restrict__ ed, const int* __restrict__ rowptr,
                                             const int* __restrict__ col, const float* __restrict__ bias,
                                             float* __restrict__ x, float* __restrict__ outacc,
                                             void* __restrict__ out, const int* __restrict__ flag,
                                             int write_out, int n) {
    int gw = (blockIdx.x * 256 + threadIdx.x) >> 6;
    int lane = threadIdx.x & 63;
    if (gw >= n) return;
    int start = rowptr[gw], end = rowptr[gw + 1];
    int deg = end - start;
    float edd = ed[gw];

    if (deg <= 64) {
        // --- one gather pass: per-lane edge cache ---
        int c = 0;
        float e = -1e30f;
        if (lane < deg) {
            c = col[start + lane];
            float t = es[c] + edd;
            e = t > 0.f ? t : 0.2f * t;
        }
        float m = e;
        #pragma unroll
        for (int off = 32; off; off >>= 1) m = fmaxf(m, __shfl_xor(m, off));
        float ex = (lane < deg) ? __expf(e - m) : 0.f;
        float sum = ex;
        #pragma unroll
        for (int off = 32; off; off >>= 1) sum += __shfl_xor(sum, off);
        float a = ex / (sum + 1e-16f);     // per-edge alpha, lane = edge slot

        // --- gather h: 4 edges in flight, 16 lanes x float4 each ---
        int g = lane >> 4, j = lane & 15;
        float4 acc = make_float4(0.f, 0.f, 0.f, 0.f);
        for (int t = 0; t < deg; t += 4) {
            int idx = t + g;
            int   s  = __shfl(c, idx);
            float al = __shfl(a, idx);
            if (idx < deg) {
                const float4 hv = *(const float4*)(h + (size_t)s * 64 + j * 4);
                acc.x = fmaf(al, hv.x, acc.x);
                acc.y = fmaf(al, hv.y, acc.y);
                acc.z = fmaf(al, hv.z, acc.z);
                acc.w = fmaf(al, hv.w, acc.w);
            }
        }
        acc.x += __shfl_xor(acc.x, 16); acc.y += __shfl_xor(acc.y, 16);
        acc.z += __shfl_xor(acc.z, 16); acc.w += __shfl_xor(acc.w, 16);
        acc.x += __shfl_xor(acc.x, 32); acc.y += __shfl_xor(acc.y, 32);
        acc.z += __shfl_xor(acc.z, 32); acc.w += __shfl_xor(acc.w, 32);

        if (g == 0) {
            const float4 bv = *(const float4*)(bias + j * 4);
            size_t base = (size_t)gw * 64 + j * 4;
            float4 y;
            y.x = elu_f(acc.x + bv.x);
            y.y = elu_f(acc.y + bv.y);
            y.z = elu_f(acc.z + bv.z);
            y.w = elu_f(acc.w + bv.w);
            float4 oa = *(const float4*)(outacc + base);
            oa.x += y.x; oa.y += y.y; oa.z += y.z; oa.w += y.w;
            if (write_out) {
                if (*flag) {
                    ushort4 o;
                    o.x = f2bf(oa.x * 0.25f); o.y = f2bf(oa.y * 0.25f);
                    o.z = f2bf(oa.z * 0.25f); o.w = f2bf(oa.w * 0.25f);
                    *(ushort4*)((unsigned short*)out + base) = o;
                } else {
                    float4 o = make_float4(oa.x * 0.25f, oa.y * 0.25f, oa.z * 0.25f, oa.w * 0.25f);
                    *(float4*)((float*)out + base) = o;
                }
            } else {
                *(float4*)(x + base) = y;
                *(float4*)(outacc + base) = oa;
            }
        }
    } else {
        // --- rare slow path: 3-pass scalar ---
        float m = -1e30f;
        for (int k = start + lane; k < end; k += 64) {
            float e = es[col[k]] + edd;
            e = e > 0.f ? e : 0.2f * e;
            m = fmaxf(m, e);
        }
        #pragma unroll
        for (int off = 32; off; off >>= 1) m = fmaxf(m, __shfl_xor(m, off));
        float sum = 0.f;
        for (int k = start + lane; k < end; k += 64) {
            float e = es[col[k]] + edd;
            e = e > 0.f ? e : 0.2f * e;
            sum += __expf(e - m);
        }
        #pragma unroll
        for (int off = 32; off; off >>= 1) sum += __shfl_xor(sum, off);
        float inv = 1.f / (sum + 1e-16f);
        float acc = 0.f;
        for (int k = start; k < end; ++k) {
            int s = col[k];
            float e = es[s] + edd;
            e = e > 0.f ? e : 0.2f * e;
            float al = __expf(e - m) * inv;
            acc = fmaf(al, h[(size_t)s * 64 + lane], acc);
        }
        size_t base = (size_t)gw * 64 + lane;
        float y = elu_f(acc + bias[lane]);
        float oa = outacc[base] + y;
        if (write_out) {
            if (*flag) ((unsigned short*)out)[base] = f2bf(oa * 0.25f);
            else       ((float*)out)[base] = oa * 0.25f;
        } else {
            x[base] = y;
            outacc[base] = oa;
        }
    }
}

// ---------------------------------------------------------------------------

extern "C" void kernel_launch(void* const* d_in, const int* in_sizes, int n_in,
                              void* d_out, int out_size, void* d_ws, size_t ws_size,
                              hipStream_t stream) {
    const int*  edge = (const int*)d_in[0];
    const void* emb  = d_in[1];
    const void* W    = d_in[2];
    const void* as_  = d_in[3];
    const void* ad_  = d_in[4];
    const void* b_   = d_in[5];

    const int E = in_sizes[0] / 2;
    const int N = in_sizes[1] / 64;
    const int L = in_sizes[2] / 4096;
    const size_t N64 = (size_t)N * 64;

    char* p = (char*)d_ws;
    auto take = [&](size_t bytes) { char* r = p; p += (bytes + 255) & ~(size_t)255; return r; };
    float* x      = (float*)take(N64 * 4);
    float* h      = (float*)take(N64 * 4);
    float* outacc = (float*)take(N64 * 4);
    float* es     = (float*)take((size_t)N * 4);
    float* ed     = (float*)take((size_t)N * 4);
    float* Wf     = (float*)take((size_t)L * 4096 * 4);
    float* asf    = (float*)take((size_t)L * 64 * 4);
    float* adf    = (float*)take((size_t)L * 64 * 4);
    float* bf     = (float*)take((size_t)L * 64 * 4);
    int* cursor   = (int*)take((size_t)N * 4);
    int* rowptr   = (int*)take((size_t)(N + 1) * 4);
    int* col      = (int*)take((size_t)(E + N) * 4);
    int* bsums    = (int*)take(512 * 4);
    int* flag     = (int*)take(4);

    const int* srcp = edge;
    const int* dstp = edge + E;

    detect_bf16_k<<<1, 256, 0, stream>>>((const unsigned int*)emb, flag);
    conv_emb_k<<<(int)((N64 + 255) / 256), 256, 0, stream>>>(emb, x, outacc, cursor, (int)N64, N, flag);
    conv_params_k<<<(L * 4096 + 255) / 256, 256, 0, stream>>>(W, as_, ad_, b_, Wf, asf, adf, bf,
                                                              L * 4096, L * 64, flag);

    // CSR build (dst-grouped), reused by all layers
    count_k<<<(E + 255) / 256, 256, 0, stream>>>(dstp, cursor, E);
    int nb1 = (N + 255) / 256;                 // 391 <= 512
    scan_block_k<<<nb1, 256, 0, stream>>>(cursor, rowptr, bsums, N);
    scan_sums_k<<<1, 512, 0, stream>>>(bsums, nb1);
    scan_add_k<<<nb1, 256, 0, stream>>>(rowptr, bsums, cursor, N, E + N);
    scatter_k<<<(E + N + 255) / 256, 256, 0, stream>>>(srcp, dstp, cursor, col, E, N);

    for (int l = 0; l < L; ++l) {
        gemm_k<<<1024, 256, 0, stream>>>(x, Wf + (size_t)l * 4096, asf + l * 64, adf + l * 64,
                                         h, es, ed, N);
        agg_k<<<(N + 3) / 4, 256, 0, stream>>>(h, es, ed, rowptr, col, bf + l * 64, x, outacc,
                                               d_out, flag, (l == L - 1) ? 1 : 0, N);
    }
}

// Round 3
// 605.505 us; speedup vs baseline: 1.8579x; 1.3113x over previous
//
#include <hip/hip_runtime.h>
#include <hip/hip_bf16.h>

// ---------------------------------------------------------------------------
// GAT forward: 3 layers, N=100k nodes, D=64, E=1.6M edges (+N self loops).
// CSR build via 2-phase bucket partition (no write-amplified global scatter):
//   hist_k -> scan_nb_k -> partition_k (LDS-binned, contiguous bucket writes)
//   -> build_k (per-bucket LDS counting sort, coalesced col/rowptr output).
// Per layer: gemm_k (h=xW + fused scores, h stored bf16), agg_k (register-
// cached edge softmax + 4-edges-in-flight bf16 row gather).
// ---------------------------------------------------------------------------

#define BSHIFT 9
#define NPB 512            // nodes per bucket
#define COL_CAP 10240      // LDS col image capacity per bucket (mean ~8700)

__device__ inline float bf2f(unsigned short u) {
    return __uint_as_float(((unsigned int)u) << 16);
}
__device__ inline unsigned short f2bf(float v) {
    __hip_bfloat16 b = __float2bfloat16(v);
    return *reinterpret_cast<unsigned short*>(&b);
}

// also zeros the bucket histogram
__global__ __launch_bounds__(256) void detect_bf16_k(const unsigned int* raw, int* flag, int* ghist) {
    __shared__ int sc;
    if (threadIdx.x == 0) sc = 0;
    ghist[threadIdx.x] = 0;
    __syncthreads();
    int c = 0;
    for (int i = threadIdx.x; i < 4096; i += 256) {
        unsigned int b = (raw[i] >> 8) & 0x7Fu;   // bits 15:8, sign masked
        if (b >= 0x3Bu && b <= 0x3Fu) c++;        // bf16 exponent byte range
    }
    atomicAdd(&sc, c);
    __syncthreads();
    if (threadIdx.x == 0) *flag = (sc > 2048) ? 1 : 0;
}

__device__ inline float load_in(const void* p, int i, int isbf) {
    if (isbf) return bf2f(((const unsigned short*)p)[i]);
    return ((const float*)p)[i];
}

__global__ __launch_bounds__(256) void conv_emb_k(const void* emb, float* x, float* outacc,
                                                  int n, const int* flag) {
    int i = blockIdx.x * 256 + threadIdx.x;
    if (i >= n) return;
    float v = load_in(emb, i, *flag);
    x[i] = v;
    outacc[i] = v;   // mean starts with x0 = emb
}

__global__ __launch_bounds__(256) void conv_params_k(const void* W, const void* as_, const void* ad_,
                                                     const void* b_, float* Wf, float* asf, float* adf,
                                                     float* bf, int nw, int na, const int* flag) {
    int i = blockIdx.x * 256 + threadIdx.x;
    int isbf = *flag;
    if (i < nw) Wf[i] = load_in(W, i, isbf);
    if (i < na) {
        asf[i] = load_in(as_, i, isbf);
        adf[i] = load_in(ad_, i, isbf);
        bf[i]  = load_in(b_,  i, isbf);
    }
}

// ---- CSR build: bucket partition ------------------------------------------

__global__ __launch_bounds__(256) void hist_k(const int* dst, int* ghist, int E) {
    __shared__ int h[256];
    h[threadIdx.x] = 0;
    __syncthreads();
    int cs = blockIdx.x * 4096;
    int ce = min(cs + 4096, E);
    for (int i = cs + threadIdx.x; i < ce; i += 256)
        atomicAdd(&h[dst[i] >> BSHIFT], 1);
    __syncthreads();
    if (h[threadIdx.x]) atomicAdd(&ghist[threadIdx.x], h[threadIdx.x]);
}

// single block: exclusive scans of pairs sizes and col sizes (edges + self loops)
__global__ __launch_bounds__(256) void scan_nb_k(const int* ghist, int* pairs_base, int* col_base,
                                                 int* cursor, int* rowptr, int N, int E, int NB) {
    __shared__ int s1[256], s2[256];
    int t = threadIdx.x;
    int hv = (t < NB) ? ghist[t] : 0;
    int npb = (t < NB) ? min(N - (t << BSHIFT), NPB) : 0;
    s1[t] = hv; s2[t] = hv + npb;
    __syncthreads();
    for (int off = 1; off < 256; off <<= 1) {
        int t1 = (t >= off) ? s1[t - off] : 0;
        int t2 = (t >= off) ? s2[t - off] : 0;
        __syncthreads();
        s1[t] += t1; s2[t] += t2;
        __syncthreads();
    }
    if (t < NB) {
        pairs_base[t] = s1[t] - hv;
        cursor[t]     = s1[t] - hv;
        col_base[t]   = s2[t] - (hv + npb);
    }
    if (t == 0) rowptr[N] = E + N;
}

// LDS-binned partition: contiguous ~128B runs per bucket per block
__global__ __launch_bounds__(256) void partition_k(const int* __restrict__ src,
                                                   const int* __restrict__ dst,
                                                   int* cursor, uint2* __restrict__ pairs,
                                                   int E, int NB) {
    __shared__ int cnt[256], base[256], rk[256];
    int t = threadIdx.x;
    cnt[t] = 0; rk[t] = 0;
    __syncthreads();
    int cs = blockIdx.x * 4096;
    int ce = min(cs + 4096, E);
    for (int i = cs + t; i < ce; i += 256)
        atomicAdd(&cnt[dst[i] >> BSHIFT], 1);
    __syncthreads();
    if (t < NB && cnt[t]) base[t] = atomicAdd(&cursor[t], cnt[t]);
    __syncthreads();
    for (int i = cs + t; i < ce; i += 256) {
        int d = dst[i];
        int b = d >> BSHIFT;
        int r = atomicAdd(&rk[b], 1);
        pairs[base[b] + r] = make_uint2((unsigned)src[i], (unsigned)d);
    }
}

// one block per bucket: counting sort in LDS, coalesced rowptr/col output
__global__ __launch_bounds__(512) void build_k(const uint2* __restrict__ pairs,
                                               const int* __restrict__ ghist,
                                               const int* __restrict__ pairs_base,
                                               const int* __restrict__ col_base,
                                               int* __restrict__ rowptr, int* __restrict__ col,
                                               int N) {
    __shared__ int cnt[512], cnt2[512], sc[512], off[513];
    __shared__ int col_lds[COL_CAP];
    int b = blockIdx.x, t = threadIdx.x;
    int nloc = min(N - (b << BSHIFT), NPB);
    int ne = ghist[b], pb = pairs_base[b], cb = col_base[b];
    cnt[t] = 0; cnt2[t] = 0;
    __syncthreads();
    for (int i = t; i < ne; i += 512)
        atomicAdd(&cnt[pairs[pb + i].y & (NPB - 1)], 1);
    __syncthreads();
    int v = cnt[t] + (t < nloc ? 1 : 0);    // +1 self loop
    sc[t] = v;
    __syncthreads();
    for (int o = 1; o < 512; o <<= 1) {
        int tv = (t >= o) ? sc[t - o] : 0;
        __syncthreads();
        sc[t] += tv;
        __syncthreads();
    }
    off[t + 1] = sc[t];
    if (t == 0) off[0] = 0;
    __syncthreads();
    if (t < nloc) rowptr[(b << BSHIFT) + t] = cb + off[t];
    int total = off[nloc];                   // == ne + nloc
    bool fit = (total <= COL_CAP);
    for (int i = t; i < ne; i += 512) {
        uint2 p = pairs[pb + i];
        int loc = p.y & (NPB - 1);
        int pos = off[loc] + atomicAdd(&cnt2[loc], 1);
        if (fit) col_lds[pos] = (int)p.x;
        else     col[cb + pos] = (int)p.x;   // overflow fallback (never in bench)
    }
    if (t < nloc) {
        int pos = off[t + 1] - 1;            // self-loop slot
        int sv = (b << BSHIFT) + t;
        if (fit) col_lds[pos] = sv;
        else     col[cb + pos] = sv;
    }
    __syncthreads();
    if (fit)
        for (int i = t; i < total; i += 512) col[cb + i] = col_lds[i];
}

// ---- per-layer compute -----------------------------------------------------

// h = x @ W  (D=64) stored bf16, fused scores es = h.a_s, ed = h.a_d (f32).
__global__ __launch_bounds__(256) void gemm_k(const float* __restrict__ x, const float* __restrict__ W,
                                              const float* __restrict__ asv, const float* __restrict__ adv,
                                              unsigned short* __restrict__ h, float* __restrict__ es,
                                              float* __restrict__ ed, int n) {
    __shared__ float Wl[4096];
    __shared__ float asl[64], adl[64];
    for (int i = threadIdx.x; i < 4096; i += 256) Wl[i] = W[i];
    if (threadIdx.x < 64) { asl[threadIdx.x] = asv[threadIdx.x]; adl[threadIdx.x] = adv[threadIdx.x]; }
    __syncthreads();
    int lane = threadIdx.x & 63;
    int wv = threadIdx.x >> 6;
    float a_s = asl[lane], a_d = adl[lane];
    for (int node = blockIdx.x * 4 + wv; node < n; node += gridDim.x * 4) {
        float xv = x[(size_t)node * 64 + lane];
        float acc = 0.f;
        #pragma unroll
        for (int k = 0; k < 64; ++k)
            acc = fmaf(__shfl(xv, k), Wl[k * 64 + lane], acc);
        h[(size_t)node * 64 + lane] = f2bf(acc);
        float s1 = acc * a_s, s2 = acc * a_d;
        #pragma unroll
        for (int off = 32; off; off >>= 1) {
            s1 += __shfl_xor(s1, off);
            s2 += __shfl_xor(s2, off);
        }
        if (lane == 0) { es[node] = s1; ed[node] = s2; }
    }
}

__device__ inline float elu_f(float v) { return v > 0.f ? v : (__expf(v) - 1.f); }

// One wave per dst node. Fast path (deg<=64): edge list cached in registers,
// one gather pass for scores, then bf16 h gathered 4 edges/iter (16 lanes x 8B).
__global__ __launch_bounds__(256) void agg_k(const unsigned short* __restrict__ h,
                                             const float* __restrict__ es,
                                             const float* __restrict__ ed, const int* __restrict__ rowptr,
                                             const int* __restrict__ col, const float* __restrict__ bias,
                                             float* __restrict__ x, float* __restrict__ outacc,
                                             void* __restrict__ out, const int* __restrict__ flag,
                                             int write_out, int n) {
    int gw = (blockIdx.x * 256 + threadIdx.x) >> 6;
    int lane = threadIdx.x & 63;
    if (gw >= n) return;
    int start = rowptr[gw], end = rowptr[gw + 1];
    int deg = end - start;
    float edd = ed[gw];

    if (deg <= 64) {
        int c = 0;
        float e = -1e30f;
        if (lane < deg) {
            c = col[start + lane];
            float t = es[c] + edd;
            e = t > 0.f ? t : 0.2f * t;
        }
        float m = e;
        #pragma unroll
        for (int off = 32; off; off >>= 1) m = fmaxf(m, __shfl_xor(m, off));
        float ex = (lane < deg) ? __expf(e - m) : 0.f;
        float sum = ex;
        #pragma unroll
        for (int off = 32; off; off >>= 1) sum += __shfl_xor(sum, off);
        float a = ex / (sum + 1e-16f);     // per-edge alpha, lane = edge slot

        int g = lane >> 4, j = lane & 15;
        float4 acc = make_float4(0.f, 0.f, 0.f, 0.f);
        for (int t = 0; t < deg; t += 4) {
            int idx = t + g;
            int   s  = __shfl(c, idx);
            float al = __shfl(a, idx);
            if (idx < deg) {
                const ushort4 hv = *(const ushort4*)(h + (size_t)s * 64 + j * 4);
                acc.x = fmaf(al, bf2f(hv.x), acc.x);
                acc.y = fmaf(al, bf2f(hv.y), acc.y);
                acc.z = fmaf(al, bf2f(hv.z), acc.z);
                acc.w = fmaf(al, bf2f(hv.w), acc.w);
            }
        }
        acc.x += __shfl_xor(acc.x, 16); acc.y += __shfl_xor(acc.y, 16);
        acc.z += __shfl_xor(acc.z, 16); acc.w += __shfl_xor(acc.w, 16);
        acc.x += __shfl_xor(acc.x, 32); acc.y += __shfl_xor(acc.y, 32);
        acc.z += __shfl_xor(acc.z, 32); acc.w += __shfl_xor(acc.w, 32);

        if (g == 0) {
            const float4 bv = *(const float4*)(bias + j * 4);
            size_t base = (size_t)gw * 64 + j * 4;
            float4 y;
            y.x = elu_f(acc.x + bv.x);
            y.y = elu_f(acc.y + bv.y);
            y.z = elu_f(acc.z + bv.z);
            y.w = elu_f(acc.w + bv.w);
            float4 oa = *(const float4*)(outacc + base);
            oa.x += y.x; oa.y += y.y; oa.z += y.z; oa.w += y.w;
            if (write_out) {
                if (*flag) {
                    ushort4 o;
                    o.x = f2bf(oa.x * 0.25f); o.y = f2bf(oa.y * 0.25f);
                    o.z = f2bf(oa.z * 0.25f); o.w = f2bf(oa.w * 0.25f);
                    *(ushort4*)((unsigned short*)out + base) = o;
                } else {
                    float4 o = make_float4(oa.x * 0.25f, oa.y * 0.25f, oa.z * 0.25f, oa.w * 0.25f);
                    *(float4*)((float*)out + base) = o;
                }
            } else {
                *(float4*)(x + base) = y;
                *(float4*)(outacc + base) = oa;
            }
        }
    } else {
        // rare slow path: 3-pass scalar
        float m = -1e30f;
        for (int k = start + lane; k < end; k += 64) {
            float e = es[col[k]] + edd;
            e = e > 0.f ? e : 0.2f * e;
            m = fmaxf(m, e);
        }
        #pragma unroll
        for (int off = 32; off; off >>= 1) m = fmaxf(m, __shfl_xor(m, off));
        float sum = 0.f;
        for (int k = start + lane; k < end; k += 64) {
            float e = es[col[k]] + edd;
            e = e > 0.f ? e : 0.2f * e;
            sum += __expf(e - m);
        }
        #pragma unroll
        for (int off = 32; off; off >>= 1) sum += __shfl_xor(sum, off);
        float inv = 1.f / (sum + 1e-16f);
        float acc = 0.f;
        for (int k = start; k < end; ++k) {
            int s = col[k];
            float e = es[s] + edd;
            e = e > 0.f ? e : 0.2f * e;
            float al = __expf(e - m) * inv;
            acc = fmaf(al, bf2f(h[(size_t)s * 64 + lane]), acc);
        }
        size_t base = (size_t)gw * 64 + lane;
        float y = elu_f(acc + bias[lane]);
        float oa = outacc[base] + y;
        if (write_out) {
            if (*flag) ((unsigned short*)out)[base] = f2bf(oa * 0.25f);
            else       ((float*)out)[base] = oa * 0.25f;
        } else {
            x[base] = y;
            outacc[base] = oa;
        }
    }
}

// ---------------------------------------------------------------------------

extern "C" void kernel_launch(void* const* d_in, const int* in_sizes, int n_in,
                              void* d_out, int out_size, void* d_ws, size_t ws_size,
                              hipStream_t stream) {
    const int*  edge = (const int*)d_in[0];
    const void* emb  = d_in[1];
    const void* W    = d_in[2];
    const void* as_  = d_in[3];
    const void* ad_  = d_in[4];
    const void* b_   = d_in[5];

    const int E = in_sizes[0] / 2;
    const int N = in_sizes[1] / 64;
    const int L = in_sizes[2] / 4096;
    const int NB = (N + NPB - 1) >> BSHIFT;     // 196 buckets (<=256)
    const size_t N64 = (size_t)N * 64;

    char* p = (char*)d_ws;
    auto take = [&](size_t bytes) { char* r = p; p += (bytes + 255) & ~(size_t)255; return r; };
    float* x       = (float*)take(N64 * 4);
    float* outacc  = (float*)take(N64 * 4);
    unsigned short* h = (unsigned short*)take(N64 * 2);
    float* es      = (float*)take((size_t)N * 4);
    float* ed      = (float*)take((size_t)N * 4);
    float* Wf      = (float*)take((size_t)L * 4096 * 4);
    float* asf     = (float*)take((size_t)L * 64 * 4);
    float* adf     = (float*)take((size_t)L * 64 * 4);
    float* bf      = (float*)take((size_t)L * 64 * 4);
    uint2* pairs   = (uint2*)take((size_t)E * 8);
    int* rowptr    = (int*)take((size_t)(N + 1) * 4);
    int* col       = (int*)take((size_t)(E + N) * 4);
    int* ghist     = (int*)take(256 * 4);
    int* pairs_base= (int*)take(256 * 4);
    int* col_base  = (int*)take(256 * 4);
    int* cursor    = (int*)take(256 * 4);
    int* flag      = (int*)take(4);

    const int* srcp = edge;
    const int* dstp = edge + E;
    int nchunk = (E + 4095) / 4096;

    detect_bf16_k<<<1, 256, 0, stream>>>((const unsigned int*)emb, flag, ghist);
    conv_emb_k<<<(int)((N64 + 255) / 256), 256, 0, stream>>>(emb, x, outacc, (int)N64, flag);
    conv_params_k<<<(L * 4096 + 255) / 256, 256, 0, stream>>>(W, as_, ad_, b_, Wf, asf, adf, bf,
                                                              L * 4096, L * 64, flag);

    hist_k<<<nchunk, 256, 0, stream>>>(dstp, ghist, E);
    scan_nb_k<<<1, 256, 0, stream>>>(ghist, pairs_base, col_base, cursor, rowptr, N, E, NB);
    partition_k<<<nchunk, 256, 0, stream>>>(srcp, dstp, cursor, pairs, E, NB);
    build_k<<<NB, 512, 0, stream>>>(pairs, ghist, pairs_base, col_base, rowptr, col, N);

    for (int l = 0; l < L; ++l) {
        gemm_k<<<1024, 256, 0, stream>>>(x, Wf + (size_t)l * 4096, asf + l * 64, adf + l * 64,
                                         h, es, ed, N);
        agg_k<<<(N + 3) / 4, 256, 0, stream>>>(h, es, ed, rowptr, col, bf + l * 64, x, outacc,
                                               d_out, flag, (l == L - 1) ? 1 : 0, N);
    }
}

// Round 4
// 371.583 us; speedup vs baseline: 3.0274x; 1.6295x over previous
//
#include <hip/hip_runtime.h>
#include <hip/hip_bf16.h>

// ---------------------------------------------------------------------------
// GAT forward: 3 layers, N=100k nodes, D=64, E=1.6M edges (+N self loops).
// CSR via 2-phase bucket partition. Per layer:
//   gemm_k: h = x @ W on MFMA (f32_16x16x32_f16), x/W/h fp16, fused scores
//           es=h.a_s, ed=h.a_d in f32 epilogue.
//   agg_k : register-cached edge softmax + 8-edges-in-flight fp16 row gather.
// fp16 internal precision: bf16 inputs convert exactly; ELU outputs quantize
// at ~5e-4 rel (better than bf16's 4e-3).
// ---------------------------------------------------------------------------

#define BSHIFT 9
#define NPB 512            // nodes per bucket
#define COL_CAP 10240      // LDS col image capacity per bucket (mean ~8700)

typedef _Float16 v8h __attribute__((ext_vector_type(8)));
typedef float v4f __attribute__((ext_vector_type(4)));
typedef unsigned short u16x8 __attribute__((ext_vector_type(8)));

__device__ inline float bf2f(unsigned short u) {
    return __uint_as_float(((unsigned int)u) << 16);
}
__device__ inline unsigned short f2bf(float v) {
    __hip_bfloat16 b = __float2bfloat16(v);
    return *reinterpret_cast<unsigned short*>(&b);
}
__device__ inline unsigned short f2h_u(float v) {
    return __builtin_bit_cast(unsigned short, (_Float16)v);
}
__device__ inline float h2f_u(unsigned short u) {
    return (float)__builtin_bit_cast(_Float16, u);
}

// also zeros the bucket histogram
__global__ __launch_bounds__(256) void detect_bf16_k(const unsigned int* raw, int* flag, int* ghist) {
    __shared__ int sc;
    if (threadIdx.x == 0) sc = 0;
    ghist[threadIdx.x] = 0;
    __syncthreads();
    int c = 0;
    for (int i = threadIdx.x; i < 4096; i += 256) {
        unsigned int b = (raw[i] >> 8) & 0x7Fu;   // bits 15:8, sign masked
        if (b >= 0x3Bu && b <= 0x3Fu) c++;        // bf16 exponent byte range
    }
    atomicAdd(&sc, c);
    __syncthreads();
    if (threadIdx.x == 0) *flag = (sc > 2048) ? 1 : 0;
}

__device__ inline float load_in(const void* p, int i, int isbf) {
    if (isbf) return bf2f(((const unsigned short*)p)[i]);
    return ((const float*)p)[i];
}

// emb -> x (fp16) + outacc (f32)
__global__ __launch_bounds__(256) void conv_emb_k(const void* emb, unsigned short* x, float* outacc,
                                                  int n, const int* flag) {
    int i = blockIdx.x * 256 + threadIdx.x;
    if (i >= n) return;
    float v = load_in(emb, i, *flag);
    x[i] = f2h_u(v);
    outacc[i] = v;   // mean starts with x0 = emb
}

__global__ __launch_bounds__(256) void conv_params_k(const void* W, const void* as_, const void* ad_,
                                                     const void* b_, unsigned short* Wh, float* asf,
                                                     float* adf, float* bf, int nw, int na,
                                                     const int* flag) {
    int i = blockIdx.x * 256 + threadIdx.x;
    int isbf = *flag;
    if (i < nw) Wh[i] = f2h_u(load_in(W, i, isbf));
    if (i < na) {
        asf[i] = load_in(as_, i, isbf);
        adf[i] = load_in(ad_, i, isbf);
        bf[i]  = load_in(b_,  i, isbf);
    }
}

// ---- CSR build: bucket partition ------------------------------------------

__global__ __launch_bounds__(256) void hist_k(const int* dst, int* ghist, int E) {
    __shared__ int h[256];
    h[threadIdx.x] = 0;
    __syncthreads();
    int cs = blockIdx.x * 4096;
    int ce = min(cs + 4096, E);
    for (int i = cs + threadIdx.x; i < ce; i += 256)
        atomicAdd(&h[dst[i] >> BSHIFT], 1);
    __syncthreads();
    if (h[threadIdx.x]) atomicAdd(&ghist[threadIdx.x], h[threadIdx.x]);
}

__global__ __launch_bounds__(256) void scan_nb_k(const int* ghist, int* pairs_base, int* col_base,
                                                 int* cursor, int* rowptr, int N, int E, int NB) {
    __shared__ int s1[256], s2[256];
    int t = threadIdx.x;
    int hv = (t < NB) ? ghist[t] : 0;
    int npb = (t < NB) ? min(N - (t << BSHIFT), NPB) : 0;
    s1[t] = hv; s2[t] = hv + npb;
    __syncthreads();
    for (int off = 1; off < 256; off <<= 1) {
        int t1 = (t >= off) ? s1[t - off] : 0;
        int t2 = (t >= off) ? s2[t - off] : 0;
        __syncthreads();
        s1[t] += t1; s2[t] += t2;
        __syncthreads();
    }
    if (t < NB) {
        pairs_base[t] = s1[t] - hv;
        cursor[t]     = s1[t] - hv;
        col_base[t]   = s2[t] - (hv + npb);
    }
    if (t == 0) rowptr[N] = E + N;
}

__global__ __launch_bounds__(256) void partition_k(const int* __restrict__ src,
                                                   const int* __restrict__ dst,
                                                   int* cursor, uint2* __restrict__ pairs,
                                                   int E, int NB) {
    __shared__ int cnt[256], base[256], rk[256];
    int t = threadIdx.x;
    cnt[t] = 0; rk[t] = 0;
    __syncthreads();
    int cs = blockIdx.x * 4096;
    int ce = min(cs + 4096, E);
    for (int i = cs + t; i < ce; i += 256)
        atomicAdd(&cnt[dst[i] >> BSHIFT], 1);
    __syncthreads();
    if (t < NB && cnt[t]) base[t] = atomicAdd(&cursor[t], cnt[t]);
    __syncthreads();
    for (int i = cs + t; i < ce; i += 256) {
        int d = dst[i];
        int b = d >> BSHIFT;
        int r = atomicAdd(&rk[b], 1);
        pairs[base[b] + r] = make_uint2((unsigned)src[i], (unsigned)d);
    }
}

__global__ __launch_bounds__(512) void build_k(const uint2* __restrict__ pairs,
                                               const int* __restrict__ ghist,
                                               const int* __restrict__ pairs_base,
                                               const int* __restrict__ col_base,
                                               int* __restrict__ rowptr, int* __restrict__ col,
                                               int N) {
    __shared__ int cnt[512], cnt2[512], sc[512], off[513];
    __shared__ int col_lds[COL_CAP];
    int b = blockIdx.x, t = threadIdx.x;
    int nloc = min(N - (b << BSHIFT), NPB);
    int ne = ghist[b], pb = pairs_base[b], cb = col_base[b];
    cnt[t] = 0; cnt2[t] = 0;
    __syncthreads();
    for (int i = t; i < ne; i += 512)
        atomicAdd(&cnt[pairs[pb + i].y & (NPB - 1)], 1);
    __syncthreads();
    int v = cnt[t] + (t < nloc ? 1 : 0);    // +1 self loop
    sc[t] = v;
    __syncthreads();
    for (int o = 1; o < 512; o <<= 1) {
        int tv = (t >= o) ? sc[t - o] : 0;
        __syncthreads();
        sc[t] += tv;
        __syncthreads();
    }
    off[t + 1] = sc[t];
    if (t == 0) off[0] = 0;
    __syncthreads();
    if (t < nloc) rowptr[(b << BSHIFT) + t] = cb + off[t];
    int total = off[nloc];                   // == ne + nloc
    bool fit = (total <= COL_CAP);
    for (int i = t; i < ne; i += 512) {
        uint2 p = pairs[pb + i];
        int loc = p.y & (NPB - 1);
        int pos = off[loc] + atomicAdd(&cnt2[loc], 1);
        if (fit) col_lds[pos] = (int)p.x;
        else     col[cb + pos] = (int)p.x;   // overflow fallback
    }
    if (t < nloc) {
        int pos = off[t + 1] - 1;            // self-loop slot
        int sv = (b << BSHIFT) + t;
        if (fit) col_lds[pos] = sv;
        else     col[cb + pos] = sv;
    }
    __syncthreads();
    if (fit)
        for (int i = t; i < total; i += 512) col[cb + i] = col_lds[i];
}

// ---- per-layer compute -----------------------------------------------------

// MFMA GEMM: h = x @ W (fp16 in, f32 acc, fp16 out), fused scores.
// Wave computes a 16-node x 64-col strip: 4 col-tiles x 2 K-frags = 8 MFMAs.
// A layout: row=lane&15, k=(lane>>4)*8+j.  B: col=lane&15, k=(lane>>4)*8+j.
// C: col=lane&15, row=(lane>>4)*4+reg.
__global__ __launch_bounds__(256) void gemm_k(const unsigned short* __restrict__ x,
                                              const unsigned short* __restrict__ Wh,
                                              const float* __restrict__ asv,
                                              const float* __restrict__ adv,
                                              unsigned short* __restrict__ h,
                                              float* __restrict__ es, float* __restrict__ ed,
                                              int n, int nblk, int nwaves) {
    int lane = threadIdx.x & 63;
    int gwave = (blockIdx.x * 256 + threadIdx.x) >> 6;
    int c = lane & 15, quad = lane >> 4;

    v8h b[4][2];
    #pragma unroll
    for (int t = 0; t < 4; ++t)
        #pragma unroll
        for (int kf = 0; kf < 2; ++kf)
            #pragma unroll
            for (int j = 0; j < 8; ++j)
                b[t][kf][j] = __builtin_bit_cast(_Float16,
                    Wh[(kf * 32 + quad * 8 + j) * 64 + t * 16 + c]);

    float as4[4], ad4[4];
    #pragma unroll
    for (int t = 0; t < 4; ++t) { as4[t] = asv[t * 16 + c]; ad4[t] = adv[t * 16 + c]; }

    for (int nb = gwave; nb < nblk; nb += nwaves) {
        int base = nb * 16;
        int m = base + c; if (m >= n) m = n - 1;
        const v8h a0 = *(const v8h*)(x + (size_t)m * 64 + quad * 8);
        const v8h a1 = *(const v8h*)(x + (size_t)m * 64 + 32 + quad * 8);
        v4f z = {0.f, 0.f, 0.f, 0.f};
        v4f acc[4];
        #pragma unroll
        for (int t = 0; t < 4; ++t) {
            acc[t] = __builtin_amdgcn_mfma_f32_16x16x32_f16(a0, b[t][0], z, 0, 0, 0);
            acc[t] = __builtin_amdgcn_mfma_f32_16x16x32_f16(a1, b[t][1], acc[t], 0, 0, 0);
        }
        // fused scores: per-row partials over this lane's 4 cols, then 16-lane reduce
        float ps[4], pd[4];
        #pragma unroll
        for (int r = 0; r < 4; ++r) {
            ps[r] = acc[0][r] * as4[0] + acc[1][r] * as4[1] + acc[2][r] * as4[2] + acc[3][r] * as4[3];
            pd[r] = acc[0][r] * ad4[0] + acc[1][r] * ad4[1] + acc[2][r] * ad4[2] + acc[3][r] * ad4[3];
        }
        #pragma unroll
        for (int off = 1; off < 16; off <<= 1)
            #pragma unroll
            for (int r = 0; r < 4; ++r) {
                ps[r] += __shfl_xor(ps[r], off);
                pd[r] += __shfl_xor(pd[r], off);
            }
        #pragma unroll
        for (int t = 0; t < 4; ++t)
            #pragma unroll
            for (int r = 0; r < 4; ++r) {
                int row = base + quad * 4 + r;
                if (row < n) h[(size_t)row * 64 + t * 16 + c] = f2h_u(acc[t][r]);
            }
        if (c == 0) {
            #pragma unroll
            for (int r = 0; r < 4; ++r) {
                int row = base + quad * 4 + r;
                if (row < n) { es[row] = ps[r]; ed[row] = pd[r]; }
            }
        }
    }
}

__device__ inline float elu_f(float v) { return v > 0.f ? v : (__expf(v) - 1.f); }

// One wave per dst node. Fast path (deg<=64): edge list cached in registers,
// one gather pass for scores, then fp16 h gathered 8 edges/iter (8 lanes x 16B).
__global__ __launch_bounds__(256) void agg_k(const unsigned short* __restrict__ h,
                                             const float* __restrict__ es,
                                             const float* __restrict__ ed, const int* __restrict__ rowptr,
                                             const int* __restrict__ col, const float* __restrict__ bias,
                                             unsigned short* __restrict__ x, float* __restrict__ outacc,
                                             void* __restrict__ out, const int* __restrict__ flag,
                                             int write_out, int n) {
    int gw = (blockIdx.x * 256 + threadIdx.x) >> 6;
    int lane = threadIdx.x & 63;
    if (gw >= n) return;
    int start = rowptr[gw], end = rowptr[gw + 1];
    int deg = end - start;
    float edd = ed[gw];

    if (deg <= 64) {
        int c = 0;
        float e = -1e30f;
        if (lane < deg) {
            c = col[start + lane];
            float t = es[c] + edd;
            e = t > 0.f ? t : 0.2f * t;
        }
        float m = e;
        #pragma unroll
        for (int off = 32; off; off >>= 1) m = fmaxf(m, __shfl_xor(m, off));
        float ex = (lane < deg) ? __expf(e - m) : 0.f;
        float sum = ex;
        #pragma unroll
        for (int off = 32; off; off >>= 1) sum += __shfl_xor(sum, off);
        float a = ex / (sum + 1e-16f);     // per-edge alpha, lane = edge slot

        int g = lane >> 3, j = lane & 7;   // 8 edge groups x 8 lanes x 16B
        float acc[8];
        #pragma unroll
        for (int i = 0; i < 8; ++i) acc[i] = 0.f;
        for (int t = 0; t < deg; t += 8) {
            int idx = t + g;
            int   s  = __shfl(c, idx);
            float al = __shfl(a, idx);
            if (idx < deg) {
                const u16x8 hv = *(const u16x8*)(h + (size_t)s * 64 + j * 8);
                #pragma unroll
                for (int i = 0; i < 8; ++i)
                    acc[i] = fmaf(al, h2f_u(hv[i]), acc[i]);
            }
        }
        #pragma unroll
        for (int off = 8; off < 64; off <<= 1)
            #pragma unroll
            for (int i = 0; i < 8; ++i)
                acc[i] += __shfl_xor(acc[i], off);

        if (g == 0) {
            size_t base = (size_t)gw * 64 + j * 8;
            float y[8], oa[8];
            #pragma unroll
            for (int i = 0; i < 8; ++i) {
                y[i] = elu_f(acc[i] + bias[j * 8 + i]);
                oa[i] = outacc[base + i] + y[i];
            }
            if (write_out) {
                if (*flag) {
                    u16x8 o;
                    #pragma unroll
                    for (int i = 0; i < 8; ++i) o[i] = f2bf(oa[i] * 0.25f);
                    *(u16x8*)((unsigned short*)out + base) = o;
                } else {
                    float4 o0 = make_float4(oa[0] * 0.25f, oa[1] * 0.25f, oa[2] * 0.25f, oa[3] * 0.25f);
                    float4 o1 = make_float4(oa[4] * 0.25f, oa[5] * 0.25f, oa[6] * 0.25f, oa[7] * 0.25f);
                    *(float4*)((float*)out + base) = o0;
                    *(float4*)((float*)out + base + 4) = o1;
                }
            } else {
                u16x8 xo;
                #pragma unroll
                for (int i = 0; i < 8; ++i) xo[i] = f2h_u(y[i]);
                *(u16x8*)(x + base) = xo;
                float4 o0 = make_float4(oa[0], oa[1], oa[2], oa[3]);
                float4 o1 = make_float4(oa[4], oa[5], oa[6], oa[7]);
                *(float4*)(outacc + base) = o0;
                *(float4*)(outacc + base + 4) = o1;
            }
        }
    } else {
        // rare slow path: 3-pass scalar
        float m = -1e30f;
        for (int k = start + lane; k < end; k += 64) {
            float e = es[col[k]] + edd;
            e = e > 0.f ? e : 0.2f * e;
            m = fmaxf(m, e);
        }
        #pragma unroll
        for (int off = 32; off; off >>= 1) m = fmaxf(m, __shfl_xor(m, off));
        float sum = 0.f;
        for (int k = start + lane; k < end; k += 64) {
            float e = es[col[k]] + edd;
            e = e > 0.f ? e : 0.2f * e;
            sum += __expf(e - m);
        }
        #pragma unroll
        for (int off = 32; off; off >>= 1) sum += __shfl_xor(sum, off);
        float inv = 1.f / (sum + 1e-16f);
        float acc = 0.f;
        for (int k = start; k < end; ++k) {
            int s = col[k];
            float e = es[s] + edd;
            e = e > 0.f ? e : 0.2f * e;
            float al = __expf(e - m) * inv;
            acc = fmaf(al, h2f_u(h[(size_t)s * 64 + lane]), acc);
        }
        size_t base = (size_t)gw * 64 + lane;
        float y = elu_f(acc + bias[lane]);
        float oa = outacc[base] + y;
        if (write_out) {
            if (*flag) ((unsigned short*)out)[base] = f2bf(oa * 0.25f);
            else       ((float*)out)[base] = oa * 0.25f;
        } else {
            x[base] = f2h_u(y);
            outacc[base] = oa;
        }
    }
}

// ---------------------------------------------------------------------------

extern "C" void kernel_launch(void* const* d_in, const int* in_sizes, int n_in,
                              void* d_out, int out_size, void* d_ws, size_t ws_size,
                              hipStream_t stream) {
    const int*  edge = (const int*)d_in[0];
    const void* emb  = d_in[1];
    const void* W    = d_in[2];
    const void* as_  = d_in[3];
    const void* ad_  = d_in[4];
    const void* b_   = d_in[5];

    const int E = in_sizes[0] / 2;
    const int N = in_sizes[1] / 64;
    const int L = in_sizes[2] / 4096;
    const int NB = (N + NPB - 1) >> BSHIFT;     // 196 buckets (<=256)
    const size_t N64 = (size_t)N * 64;

    char* p = (char*)d_ws;
    auto take = [&](size_t bytes) { char* r = p; p += (bytes + 255) & ~(size_t)255; return r; };
    unsigned short* x = (unsigned short*)take(N64 * 2);
    unsigned short* h = (unsigned short*)take(N64 * 2);
    float* outacc  = (float*)take(N64 * 4);
    float* es      = (float*)take((size_t)N * 4);
    float* ed      = (float*)take((size_t)N * 4);
    unsigned short* Wh = (unsigned short*)take((size_t)L * 4096 * 2);
    float* asf     = (float*)take((size_t)L * 64 * 4);
    float* adf     = (float*)take((size_t)L * 64 * 4);
    float* bf      = (float*)take((size_t)L * 64 * 4);
    uint2* pairs   = (uint2*)take((size_t)E * 8);
    int* rowptr    = (int*)take((size_t)(N + 1) * 4);
    int* col       = (int*)take((size_t)(E + N) * 4);
    int* ghist     = (int*)take(256 * 4);
    int* pairs_base= (int*)take(256 * 4);
    int* col_base  = (int*)take(256 * 4);
    int* cursor    = (int*)take(256 * 4);
    int* flag      = (int*)take(4);

    const int* srcp = edge;
    const int* dstp = edge + E;
    int nchunk = (E + 4095) / 4096;

    detect_bf16_k<<<1, 256, 0, stream>>>((const unsigned int*)emb, flag, ghist);
    conv_emb_k<<<(int)((N64 + 255) / 256), 256, 0, stream>>>(emb, x, outacc, (int)N64, flag);
    conv_params_k<<<(L * 4096 + 255) / 256, 256, 0, stream>>>(W, as_, ad_, b_, Wh, asf, adf, bf,
                                                              L * 4096, L * 64, flag);

    hist_k<<<nchunk, 256, 0, stream>>>(dstp, ghist, E);
    scan_nb_k<<<1, 256, 0, stream>>>(ghist, pairs_base, col_base, cursor, rowptr, N, E, NB);
    partition_k<<<nchunk, 256, 0, stream>>>(srcp, dstp, cursor, pairs, E, NB);
    build_k<<<NB, 512, 0, stream>>>(pairs, ghist, pairs_base, col_base, rowptr, col, N);

    const int nblk = (N + 15) / 16;
    const int ggrid = 400;                      // 1600 waves, ~4 blocks each
    for (int l = 0; l < L; ++l) {
        gemm_k<<<ggrid, 256, 0, stream>>>(x, Wh + (size_t)l * 4096, asf + l * 64, adf + l * 64,
                                          h, es, ed, N, nblk, ggrid * 4);
        agg_k<<<(N + 3) / 4, 256, 0, stream>>>(h, es, ed, rowptr, col, bf + l * 64, x, outacc,
                                               d_out, flag, (l == L - 1) ? 1 : 0, N);
    }
}